// Round 1
// baseline (517.421 us; speedup 1.0000x reference)
//
#include <hip/hip_runtime.h>

// EGNN — algebraic collapse:
//   alpha = outer(v,v)/S is rank-1; v = first 32 rows of normalized Ep;
//   S = 8192 exactly (each normalized row sums to 1).
//   out[i,:] = softmax(v_i/S * (W @ (X^T v)) + b).
// We never form Ep beyond its first 32 rows and never read 255/256 of E.
//
// R1 restructure vs 469us baseline:
//  - k_ep: g read ONCE (was 8x), all 32 j-rows per block, LDS-staged E tile
//  - part scratch lives in the alpha output region (written only at the end)
//  - k_out + k_alpha fused: softmax hides under the 268MB alpha write (nt stores)
//  - s-scalar folded into k_g; k_u widened to 256 blocks; 6 launches (was 8)

#define LEAKY 0.01f
constexpr float INV_S = 1.0f / 8192.0f;

typedef float v4f __attribute__((ext_vector_type(4)));

// ---- kernel A: g = exp(leakyrelu(s*(X @ W^T + b))), s computed in-block ---
__global__ __launch_bounds__(256) void k_g(const float* __restrict__ X,
                                           const float* __restrict__ W,
                                           const float* __restrict__ b,
                                           const float* __restrict__ Ai,
                                           const float* __restrict__ Aj,
                                           float* __restrict__ g) {
    __shared__ float4 Xs[16 * 32];  // 16 rows x 128 floats
    __shared__ float sred[4];
    int tid = threadIdx.x;

    // s = sum(Ai)+sum(Aj), redundant per block (1KB of L2 reads)
    float val = (tid < 128) ? Ai[tid] : Aj[tid - 128];
    for (int off = 32; off > 0; off >>= 1) val += __shfl_down(val, off, 64);
    if ((tid & 63) == 0) sred[tid >> 6] = val;

    int row0 = blockIdx.x * 16;
    const float4* X4 = (const float4*)(X + (size_t)row0 * 128);
    Xs[tid] = X4[tid];
    Xs[tid + 256] = X4[tid + 256];
    __syncthreads();

    float s = sred[0] + sred[1] + sred[2] + sred[3];
    float bk = b[tid];
    const float4* W4 = (const float4*)(W + (size_t)tid * 128);

    float acc[16];
#pragma unroll
    for (int r = 0; r < 16; r++) acc[r] = 0.f;

    for (int c4 = 0; c4 < 32; c4++) {
        float4 w = W4[c4];
#pragma unroll
        for (int r = 0; r < 16; r++) {
            float4 x = Xs[r * 32 + c4];
            acc[r] += w.x * x.x + w.y * x.y + w.z * x.z + w.w * x.w;
        }
    }
#pragma unroll
    for (int r = 0; r < 16; r++) {
        float a = s * (acc[r] + bk);
        float lr = (a >= 0.f) ? a : LEAKY * a;
        g[(size_t)(row0 + r) * 256 + tid] = expf(lr);
    }
}

// ---- kernel B: Ep partials. 128 blocks; block p: m in [p*64,p*64+64),
// ALL 32 j rows (g read once total). E tile staged in LDS as float4.
// part[j][p][k] = sum_{m in chunk} E[j,m]*g[m,k]
__global__ __launch_bounds__(256) void k_ep(const float* __restrict__ E,
                                            const float* __restrict__ g,
                                            float* __restrict__ part) {
    __shared__ float4 Es4[32][16];  // 32 j x 64 m
    int tid = threadIdx.x;
    int p = blockIdx.x;  // 0..127
    int m0 = p * 64;
    {
        int j = tid >> 3;  // 0..31
        int q = tid & 7;   // 0..7
        const float4* Erow = (const float4*)(E + (size_t)j * 8192 + m0);
        Es4[j][q] = Erow[q];
        Es4[j][q + 8] = Erow[q + 8];
    }
    __syncthreads();

    float acc[32];
#pragma unroll
    for (int j = 0; j < 32; j++) acc[j] = 0.f;

    const float* gp = g + (size_t)m0 * 256 + tid;
#pragma unroll 2
    for (int mg = 0; mg < 16; mg++) {
        float gv0 = gp[(size_t)(mg * 4 + 0) * 256];
        float gv1 = gp[(size_t)(mg * 4 + 1) * 256];
        float gv2 = gp[(size_t)(mg * 4 + 2) * 256];
        float gv3 = gp[(size_t)(mg * 4 + 3) * 256];
#pragma unroll
        for (int j = 0; j < 32; j++) {
            float4 e = Es4[j][mg];  // LDS broadcast, conflict-free
            acc[j] += e.x * gv0 + e.y * gv1 + e.z * gv2 + e.w * gv3;
        }
    }
#pragma unroll
    for (int j = 0; j < 32; j++)
        part[((size_t)j * 128 + p) * 256 + tid] = acc[j];
}

// ---- kernel C: v[j*256+k] = Ep[j,k]/rowsum_j. 32 blocks x 1024 threads ---
__global__ __launch_bounds__(1024) void k_v(const float* __restrict__ part,
                                            float* __restrict__ v) {
    int tid = threadIdx.x;
    int k = tid & 255;
    int q = tid >> 8;  // 0..3
    int j = blockIdx.x;
    const float* base = part + (size_t)j * 128 * 256 + k;
    float a = 0.f;
    for (int p = q * 32; p < q * 32 + 32; p++) a += base[(size_t)p * 256];
    __shared__ float red[1024];
    red[tid] = a;
    __syncthreads();
    float ep = 0.f;
    if (q == 0) ep = red[k] + red[k + 256] + red[k + 512] + red[k + 768];
    float w = ep;  // q>0 contributes 0
    for (int off = 32; off > 0; off >>= 1) w += __shfl_down(w, off, 64);
    __shared__ float red4[16];
    if ((tid & 63) == 0) red4[tid >> 6] = w;
    __syncthreads();
    if (q == 0) {
        float r = red4[0] + red4[1] + red4[2] + red4[3];
        v[(size_t)j * 256 + k] = ep / r;
    }
}

// ---- kernel D: u-partials: upart[blk][c] = sum over 32 rows of v[i]*X[i,c]
__global__ __launch_bounds__(256) void k_u(const float* __restrict__ X,
                                           const float* __restrict__ v,
                                           float* __restrict__ upart) {
    int tid = threadIdx.x;
    int c = tid & 127;
    int h = tid >> 7;  // 0/1
    int i0 = blockIdx.x * 32 + h * 16;
    float acc = 0.f;
    for (int t = 0; t < 16; t++) {
        int i = i0 + t;
        acc += v[i] * X[(size_t)i * 128 + c];
    }
    __shared__ float red[256];
    red[tid] = acc;
    __syncthreads();
    if (tid < 128) upart[(size_t)blockIdx.x * 128 + tid] = red[tid] + red[tid + 128];
}

// ---- kernel E: y = W @ u (u reduced from 256 partials) -------------------
__global__ __launch_bounds__(256) void k_y(const float* __restrict__ upart,
                                           const float* __restrict__ W,
                                           float* __restrict__ y) {
    __shared__ float u[128];
    int k = threadIdx.x;
    if (k < 128) {
        float a = 0.f;
        for (int bb = 0; bb < 256; bb++) a += upart[(size_t)bb * 128 + k];
        u[k] = a;
    }
    __syncthreads();
    float acc = 0.f;
    for (int c = 0; c < 128; c++) acc += W[(size_t)k * 128 + c] * u[c];
    y[k] = acc;
}

// ---- kernel F: fused softmax-out + alpha write. 2048 blocks x 4 rows -----
// out[i,:] = softmax(v[i]*INV_S*y + b); alpha[i,:] = (v[i]*INV_S) * v
// alpha stores nontemporal: 268MB streamed, no later consumer.
__global__ __launch_bounds__(256) void k_out_alpha(const float* __restrict__ v,
                                                   const float* __restrict__ y,
                                                   const float* __restrict__ b,
                                                   float* __restrict__ out,
                                                   float* __restrict__ alpha) {
    int k = threadIdx.x;
    float yk = y[k];
    float bk = b[k];
    const float4* v4 = (const float4*)v;
    float4 vv[8];
#pragma unroll
    for (int jj = 0; jj < 8; jj++) vv[jj] = v4[k + jj * 256];
    __shared__ float red[4];
#pragma unroll 1
    for (int rr = 0; rr < 4; rr++) {
        int i = blockIdx.x * 4 + rr;
        float vi = v[i] * INV_S;
        float z = vi * yk + bk;
        float m = z;
        for (int off = 32; off > 0; off >>= 1) m = fmaxf(m, __shfl_down(m, off, 64));
        if ((k & 63) == 0) red[k >> 6] = m;
        __syncthreads();
        m = fmaxf(fmaxf(red[0], red[1]), fmaxf(red[2], red[3]));
        __syncthreads();
        float e = expf(z - m);
        float ssum = e;
        for (int off = 32; off > 0; off >>= 1) ssum += __shfl_down(ssum, off, 64);
        if ((k & 63) == 0) red[k >> 6] = ssum;
        __syncthreads();
        ssum = red[0] + red[1] + red[2] + red[3];
        out[(size_t)i * 256 + k] = e / ssum;

        float* A = alpha + (size_t)i * 8192;
#pragma unroll
        for (int jj = 0; jj < 8; jj++) {
            float4 t = vv[jj];
            v4f sv = {t.x * vi, t.y * vi, t.z * vi, t.w * vi};
            __builtin_nontemporal_store(sv, (v4f*)A + k + jj * 256);
        }
        __syncthreads();  // red reused next rr
    }
}

extern "C" void kernel_launch(void* const* d_in, const int* in_sizes, int n_in,
                              void* d_out, int out_size, void* d_ws, size_t ws_size,
                              hipStream_t stream) {
    const float* X  = (const float*)d_in[0];  // 8192 x 128
    const float* E  = (const float*)d_in[1];  // 8192 x 8192
    const float* W  = (const float*)d_in[2];  // 256 x 128
    const float* b  = (const float*)d_in[3];  // 256
    const float* Ai = (const float*)d_in[4];  // 128
    const float* Aj = (const float*)d_in[5];  // 128

    float* out   = (float*)d_out;             // 8192*256
    float* alpha = out + 2097152;             // 8192*8192

    // part scratch (32*128*256 = 1M floats = 4MB) lives at the START of the
    // alpha output region: alpha is only written by the final fused kernel,
    // and k_v consumes part before that launch (stream-ordered).
    float* part  = alpha;

    float* ws    = (float*)d_ws;
    float* g     = ws;                        // 2097152
    float* v     = g + 2097152;               // 8192
    float* upart = v + 8192;                  // 256*128 = 32768
    float* y     = upart + 32768;             // 256

    k_g<<<512, 256, 0, stream>>>(X, W, b, Ai, Aj, g);
    k_ep<<<128, 256, 0, stream>>>(E, g, part);
    k_v<<<32, 1024, 0, stream>>>(part, v);
    k_u<<<256, 256, 0, stream>>>(X, v, upart);
    k_y<<<1, 256, 0, stream>>>(upart, W, y);
    k_out_alpha<<<2048, 256, 0, stream>>>(v, y, b, out, alpha);
}

// Round 2
// 458.308 us; speedup vs baseline: 1.1290x; 1.1290x over previous
//
#include <hip/hip_runtime.h>

// EGNN — algebraic collapse:
//   alpha = outer(v,v)/S is rank-1; v = first 32 rows of normalized Ep;
//   S = 8192 exactly (each normalized row sums to 1).
//   out[i,:] = softmax(v_i/S * (W @ (X^T v)) + b).
// We never form Ep beyond its first 32 rows and never read 255/256 of E.
//
// R2 vs R1 (517us):
//  - k_out_alpha: NT stores -> REGULAR stores (fill kernel proves 4.85TB/s with
//    regular stores); softmax hoisted so the 268MB alpha stream is one
//    uninterrupted run of float4 stores (2 barriers/block, was 12).
//  - y = W@u computed redundantly per block in k_out_alpha (kills k_y launch).
//  - k_u folded into k_v (k_vu): 4 launches total (was 6).

#define LEAKY 0.01f
constexpr float INV_S = 1.0f / 8192.0f;

// ---- kernel A: g = exp(leakyrelu(s*(X @ W^T + b))), s computed in-block ---
__global__ __launch_bounds__(256) void k_g(const float* __restrict__ X,
                                           const float* __restrict__ W,
                                           const float* __restrict__ b,
                                           const float* __restrict__ Ai,
                                           const float* __restrict__ Aj,
                                           float* __restrict__ g) {
    __shared__ float4 Xs[16 * 32];  // 16 rows x 128 floats
    __shared__ float sred[4];
    int tid = threadIdx.x;

    // s = sum(Ai)+sum(Aj), redundant per block (1KB of L2 reads)
    float val = (tid < 128) ? Ai[tid] : Aj[tid - 128];
    for (int off = 32; off > 0; off >>= 1) val += __shfl_down(val, off, 64);
    if ((tid & 63) == 0) sred[tid >> 6] = val;

    int row0 = blockIdx.x * 16;
    const float4* X4 = (const float4*)(X + (size_t)row0 * 128);
    Xs[tid] = X4[tid];
    Xs[tid + 256] = X4[tid + 256];
    __syncthreads();

    float s = sred[0] + sred[1] + sred[2] + sred[3];
    float bk = b[tid];
    const float4* W4 = (const float4*)(W + (size_t)tid * 128);

    float acc[16];
#pragma unroll
    for (int r = 0; r < 16; r++) acc[r] = 0.f;

    for (int c4 = 0; c4 < 32; c4++) {
        float4 w = W4[c4];
#pragma unroll
        for (int r = 0; r < 16; r++) {
            float4 x = Xs[r * 32 + c4];
            acc[r] += w.x * x.x + w.y * x.y + w.z * x.z + w.w * x.w;
        }
    }
#pragma unroll
    for (int r = 0; r < 16; r++) {
        float a = s * (acc[r] + bk);
        float lr = (a >= 0.f) ? a : LEAKY * a;
        g[(size_t)(row0 + r) * 256 + tid] = expf(lr);
    }
}

// ---- kernel B: Ep partials. 128 blocks; block p: m in [p*64,p*64+64),
// ALL 32 j rows (g read once total). E tile staged in LDS as float4.
// part[j][p][k] = sum_{m in chunk} E[j,m]*g[m,k]
__global__ __launch_bounds__(256) void k_ep(const float* __restrict__ E,
                                            const float* __restrict__ g,
                                            float* __restrict__ part) {
    __shared__ float4 Es4[32][16];  // 32 j x 64 m
    int tid = threadIdx.x;
    int p = blockIdx.x;  // 0..127
    int m0 = p * 64;
    {
        int j = tid >> 3;  // 0..31
        int q = tid & 7;   // 0..7
        const float4* Erow = (const float4*)(E + (size_t)j * 8192 + m0);
        Es4[j][q] = Erow[q];
        Es4[j][q + 8] = Erow[q + 8];
    }
    __syncthreads();

    float acc[32];
#pragma unroll
    for (int j = 0; j < 32; j++) acc[j] = 0.f;

    const float* gp = g + (size_t)m0 * 256 + tid;
#pragma unroll 2
    for (int mg = 0; mg < 16; mg++) {
        float gv0 = gp[(size_t)(mg * 4 + 0) * 256];
        float gv1 = gp[(size_t)(mg * 4 + 1) * 256];
        float gv2 = gp[(size_t)(mg * 4 + 2) * 256];
        float gv3 = gp[(size_t)(mg * 4 + 3) * 256];
#pragma unroll
        for (int j = 0; j < 32; j++) {
            float4 e = Es4[j][mg];  // LDS broadcast, conflict-free
            acc[j] += e.x * gv0 + e.y * gv1 + e.z * gv2 + e.w * gv3;
        }
    }
#pragma unroll
    for (int j = 0; j < 32; j++)
        part[((size_t)j * 128 + p) * 256 + tid] = acc[j];
}

// ---- kernel C: k_vu. 32 blocks x 1024 threads.
// Phase 1: v[j*256+k] = Ep[j,k]/rowsum_j (reduce part over 128 p-chunks).
// Phase 2: upart[j*128+c] = sum_{t<256} v[j*256+t] * X[j*256+t][c].
__global__ __launch_bounds__(1024) void k_vu(const float* __restrict__ part,
                                             const float* __restrict__ X,
                                             float* __restrict__ v,
                                             float* __restrict__ upart) {
    int tid = threadIdx.x;
    int k = tid & 255;
    int q = tid >> 8;  // 0..3
    int j = blockIdx.x;

    const float* base = part + (size_t)j * 128 * 256 + k;
    float a = 0.f;
    for (int p = q * 32; p < q * 32 + 32; p++) a += base[(size_t)p * 256];
    __shared__ float red[1024];
    __shared__ float v_s[256];
    __shared__ float red4[16];
    red[tid] = a;
    __syncthreads();

    float ep = 0.f;
    if (q == 0) ep = red[k] + red[k + 256] + red[k + 512] + red[k + 768];
    float w = ep;  // q>0 contributes 0
    for (int off = 32; off > 0; off >>= 1) w += __shfl_down(w, off, 64);
    if ((tid & 63) == 0) red4[tid >> 6] = w;
    __syncthreads();
    if (q == 0) {
        float r = red4[0] + red4[1] + red4[2] + red4[3];
        float vk = ep / r;
        v[(size_t)j * 256 + k] = vk;
        v_s[k] = vk;
    }
    __syncthreads();

    // phase 2: 1024 threads = 128 c x 8 groups; group handles 32 rows
    int c = tid & 127;
    int grp = tid >> 7;  // 0..7
    const float* Xp = X + ((size_t)j * 256 + grp * 32) * 128 + c;
    float acc = 0.f;
#pragma unroll 4
    for (int t = 0; t < 32; t++) acc += v_s[grp * 32 + t] * Xp[(size_t)t * 128];
    red[tid] = acc;
    __syncthreads();
    if (tid < 128) {
        float s = 0.f;
#pragma unroll
        for (int gg = 0; gg < 8; gg++) s += red[gg * 128 + tid];
        upart[(size_t)j * 128 + tid] = s;
    }
}

// ---- kernel D: fused y-compute + softmax-out + alpha write ---------------
// 2048 blocks x 4 rows. Per block: u = reduce(upart) [16KB L2], y[k]=W[k,:].u,
// softmax for 4 rows (2 barriers), then ONE uninterrupted regular-store
// stream: 4 rows x 8 float4 alpha stores per thread.
__global__ __launch_bounds__(256) void k_out_alpha(const float* __restrict__ v,
                                                   const float* __restrict__ upart,
                                                   const float* __restrict__ W,
                                                   const float* __restrict__ b,
                                                   float* __restrict__ out,
                                                   float* __restrict__ alpha) {
    __shared__ float u_s[128];
    __shared__ float redm[4][4];
    __shared__ float reds[4][4];
    int k = threadIdx.x;

    // u[c] = sum over 32 j-partials (identical in every block -> y identical)
    if (k < 128) {
        float s = 0.f;
#pragma unroll 8
        for (int jb = 0; jb < 32; jb++) s += upart[(size_t)jb * 128 + k];
        u_s[k] = s;
    }
    // preload v (independent of u_s)
    const float4* v4 = (const float4*)v;
    float4 vv[8];
#pragma unroll
    for (int jj = 0; jj < 8; jj++) vv[jj] = v4[k + jj * 256];
    __syncthreads();

    // y[k] = W[k,:] . u
    const float4* W4 = (const float4*)(W + (size_t)k * 128);
    const float4* u4 = (const float4*)u_s;
    float yk = 0.f;
#pragma unroll 8
    for (int c4 = 0; c4 < 32; c4++) {
        float4 w = W4[c4];
        float4 uu = u4[c4];
        yk += w.x * uu.x + w.y * uu.y + w.z * uu.z + w.w * uu.w;
    }
    float bk = b[k];
    int i0 = blockIdx.x * 4;

    // softmax for 4 rows, batched: 2 barriers total
    float vi[4], e[4];
#pragma unroll
    for (int rr = 0; rr < 4; rr++) {
        vi[rr] = v[i0 + rr] * INV_S;
        float z = vi[rr] * yk + bk;
        float mm = z;
        for (int off = 32; off > 0; off >>= 1) mm = fmaxf(mm, __shfl_down(mm, off, 64));
        if ((k & 63) == 0) redm[rr][k >> 6] = mm;
        e[rr] = z;  // stash z
    }
    __syncthreads();
#pragma unroll
    for (int rr = 0; rr < 4; rr++) {
        float mm = fmaxf(fmaxf(redm[rr][0], redm[rr][1]), fmaxf(redm[rr][2], redm[rr][3]));
        float ee = expf(e[rr] - mm);
        e[rr] = ee;
        float ss = ee;
        for (int off = 32; off > 0; off >>= 1) ss += __shfl_down(ss, off, 64);
        if ((k & 63) == 0) reds[rr][k >> 6] = ss;
    }
    __syncthreads();
#pragma unroll
    for (int rr = 0; rr < 4; rr++) {
        float ss = reds[rr][0] + reds[rr][1] + reds[rr][2] + reds[rr][3];
        out[(size_t)(i0 + rr) * 256 + k] = e[rr] / ss;
    }

    // pure alpha store stream: 32 back-to-back float4 regular stores/thread
#pragma unroll
    for (int rr = 0; rr < 4; rr++) {
        float sc = vi[rr];
        float4* A4 = (float4*)(alpha + (size_t)(i0 + rr) * 8192);
#pragma unroll
        for (int jj = 0; jj < 8; jj++) {
            float4 t = vv[jj];
            A4[k + jj * 256] = make_float4(t.x * sc, t.y * sc, t.z * sc, t.w * sc);
        }
    }
}

extern "C" void kernel_launch(void* const* d_in, const int* in_sizes, int n_in,
                              void* d_out, int out_size, void* d_ws, size_t ws_size,
                              hipStream_t stream) {
    const float* X  = (const float*)d_in[0];  // 8192 x 128
    const float* E  = (const float*)d_in[1];  // 8192 x 8192
    const float* W  = (const float*)d_in[2];  // 256 x 128
    const float* b  = (const float*)d_in[3];  // 256
    const float* Ai = (const float*)d_in[4];  // 128
    const float* Aj = (const float*)d_in[5];  // 128

    float* out   = (float*)d_out;             // 8192*256
    float* alpha = out + 2097152;             // 8192*8192

    // part scratch (32*128*256 = 4MB) lives at the START of the alpha output
    // region: alpha is only written by the final fused kernel, and k_vu
    // consumes part before that launch (stream-ordered).
    float* part  = alpha;

    float* ws    = (float*)d_ws;
    float* g     = ws;                        // 2097152
    float* v     = g + 2097152;               // 8192
    float* upart = v + 8192;                  // 32*128 = 4096

    k_g<<<512, 256, 0, stream>>>(X, W, b, Ai, Aj, g);
    k_ep<<<128, 256, 0, stream>>>(E, g, part);
    k_vu<<<32, 1024, 0, stream>>>(part, X, v, upart);
    k_out_alpha<<<2048, 256, 0, stream>>>(v, upart, W, b, out, alpha);
}